// Round 1
// baseline (9516.260 us; speedup 1.0000x reference)
//
#include <hip/hip_runtime.h>
#include <cstdint>

#define BB 128
#define SS 1024
#define HH 256
#define GG 768
#define LOG2E 1.44269504088896340736f

typedef __attribute__((ext_vector_type(8))) __bf16 bf16x8;
typedef __attribute__((ext_vector_type(4))) __bf16 bf16x4;
typedef __attribute__((ext_vector_type(4))) float f32x4;

static __device__ __forceinline__ f32x4 mfma16(bf16x8 a, bf16x8 b, f32x4 c) {
    return __builtin_amdgcn_mfma_f32_16x16x32_bf16(a, b, c, 0, 0, 0);
}

// load 8 consecutive fp32, convert to a bf16x8 fragment (lane's k-chunk)
static __device__ __forceinline__ bf16x8 load_w8(const float* __restrict__ p) {
    f32x4 a = *(const f32x4*)p;
    f32x4 b = *(const f32x4*)(p + 4);
    bf16x8 v;
    v[0] = (__bf16)a[0]; v[1] = (__bf16)a[1]; v[2] = (__bf16)a[2]; v[3] = (__bf16)a[3];
    v[4] = (__bf16)b[0]; v[5] = (__bf16)b[1]; v[6] = (__bf16)b[2]; v[7] = (__bf16)b[3];
    return v;
}

// ---------------------------------------------------------------------------
// K1: ih[t][b][g] = sum_k X[b][t][k] * Wih[g][k]   (bf16 output to workspace)
// grid: oct(128) x grp(8) x gate(3) = 3072 wgs, 512 threads.
// A = Wih slice (M=out, reg-cached frags), B = x (N=batch).
// ---------------------------------------------------------------------------
__global__ __launch_bounds__(512, 2) void k_ih(
    const float* __restrict__ X, const float* __restrict__ Wih,
    __bf16* __restrict__ ih)
{
    const int wg   = blockIdx.x;
    const int gate = wg % 3;
    const int grp  = (wg / 3) & 7;
    const int oct  = wg / 24;
    const int tid  = threadIdx.x;
    const int w = tid >> 6;
    const int l = tid & 63;
    const int c = l & 15, q = l >> 4;

    // wave w owns out-tiles 2w, 2w+1 inside this gate's 256 outputs
    bf16x8 wf[2][8];
#pragma unroll
    for (int jj = 0; jj < 2; ++jj) {
        const float* wp = Wih + (size_t)(gate * 256 + (2 * w + jj) * 16 + c) * HH + q * 8;
#pragma unroll
        for (int kf = 0; kf < 8; ++kf) wf[jj][kf] = load_w8(wp + kf * 32);
    }

    const int b = grp * 16 + c;
    const float* xbase = X + ((size_t)b * SS + (size_t)oct * 8) * HH + q * 8;
    __bf16* obase = ih + ((size_t)(oct * 8) * BB + b) * GG + gate * 256 + q * 4;

#pragma unroll 1
    for (int t8 = 0; t8 < 8; ++t8) {
        const float* xp = xbase + (size_t)t8 * HH;
        f32x4 acc0 = {0.f, 0.f, 0.f, 0.f};
        f32x4 acc1 = {0.f, 0.f, 0.f, 0.f};
#pragma unroll
        for (int kh = 0; kh < 2; ++kh) {
            bf16x8 xb[4];
#pragma unroll
            for (int kf = 0; kf < 4; ++kf) xb[kf] = load_w8(xp + kh * 128 + kf * 32);
#pragma unroll
            for (int kf = 0; kf < 4; ++kf) {
                acc0 = mfma16(wf[0][kh * 4 + kf], xb[kf], acc0);
                acc1 = mfma16(wf[1][kh * 4 + kf], xb[kf], acc1);
            }
        }
        // D: col = lane&15 = batch, row = (lane>>4)*4 + r = out-within-tile
        __bf16* op = obase + (size_t)t8 * BB * GG;
        bf16x4 o0, o1;
#pragma unroll
        for (int r = 0; r < 4; ++r) { o0[r] = (__bf16)acc0[r]; o1[r] = (__bf16)acc1[r]; }
        *(bf16x4*)(op + (2 * w + 0) * 16) = o0;
        *(bf16x4*)(op + (2 * w + 1) * 16) = o1;
    }
}

// ---------------------------------------------------------------------------
// K2: sequential GRU scan for one layer. 8 wgs (one per 16-batch group),
// 512 threads (8 waves). W_hh resident: 4 tiles/wave in VGPR + 2 tiles/wave
// in LDS. h in LDS (bf16, XOR bank swizzle). Wave w owns out-tiles {w+8j},
// j=0..5: j=0,1 gate r; j=2,3 gate z; j=4,5 gate n (pairs with j-4 lanewise).
// ---------------------------------------------------------------------------
__global__ __launch_bounds__(512, 2) void k_rec(
    const __bf16* __restrict__ ih, const float* __restrict__ Whh,
    const float* __restrict__ hx, const float* __restrict__ gamma,
    const float* __restrict__ beta, float* __restrict__ Y)
{
    extern __shared__ __align__(16) char lds[];
    char*  wlds = lds;                          // 131072 B: 128 frags x 1KB
    char*  hbuf = lds + 131072;                 // 8192 B: h[16][256] bf16 swizzled
    float* part = (float*)(lds + 139264);       // 3072 B: partial sums [24][16][2]
    float* mu   = (float*)(lds + 142336);       // 384 B: mean/rstd [3][16][2]
    float* gb   = (float*)(lds + 142720);       // 6144 B: prescaled gamma|beta
    // total 148864

    const int grp = blockIdx.x;
    const int tid = threadIdx.x;
    const int w = tid >> 6;
    const int l = tid & 63;
    const int c = l & 15, q = l >> 4;

    // gamma/beta prescaled by -log2e (sigmoid gates) / -2*log2e (tanh gate)
    for (int idx = tid; idx < GG; idx += 512) {
        float sc = (idx >= 512) ? (-2.0f * LOG2E) : (-LOG2E);
        gb[idx]      = gamma[idx] * sc;
        gb[GG + idx] = beta[idx]  * sc;
    }
    // h init (bf16, swizzled: byte(b,k) = b*512 + ((2k) ^ ((b&7)<<4)))
    for (int idx = tid; idx < 16 * HH; idx += 512) {
        int b = idx >> 8, k = idx & 255;
        *(__bf16*)(hbuf + b * 512 + ((2 * k) ^ ((b & 7) << 4))) =
            (__bf16)hx[(size_t)(grp * 16 + b) * HH + k];
    }
    // weight fragments: j=0..3 to regs, j=4,5 to LDS
    bf16x8 wf[4][8];
#pragma unroll
    for (int j = 0; j < 4; ++j) {
        const float* wp = Whh + (size_t)((w + 8 * j) * 16 + c) * HH + q * 8;
#pragma unroll
        for (int kf = 0; kf < 8; ++kf) wf[j][kf] = load_w8(wp + kf * 32);
    }
#pragma unroll
    for (int j = 4; j < 6; ++j) {
        const float* wp = Whh + (size_t)((w + 8 * j) * 16 + c) * HH + q * 8;
#pragma unroll
        for (int kf = 0; kf < 8; ++kf) {
            bf16x8 v = load_w8(wp + kf * 32);
            *(bf16x8*)(wlds + (((w * 2 + (j - 4)) * 8 + kf) << 10) + l * 16) = v;
        }
    }
    __syncthreads();

    const __bf16* ihp = ih + ((size_t)grp * 16 + c) * GG;
    float* yb = Y + (size_t)(grp * 16 + c) * SS * HH;

#pragma unroll 1
    for (int t = 0; t < SS; ++t) {
        const __bf16* ihq = ihp + (size_t)t * BB * GG;
        bf16x4 ihv[6];
#pragma unroll
        for (int j = 0; j < 6; ++j)
            ihv[j] = *(const bf16x4*)(ihq + (w + 8 * j) * 16 + q * 4);

        f32x4 acc[6];
#pragma unroll
        for (int j = 0; j < 6; ++j) acc[j] = (f32x4){0.f, 0.f, 0.f, 0.f};

#pragma unroll
        for (int kh = 0; kh < 2; ++kh) {
            bf16x8 hb[4];
#pragma unroll
            for (int kf = 0; kf < 4; ++kf) {
                int k0 = kh * 128 + kf * 32 + q * 8;
                hb[kf] = *(const bf16x8*)(hbuf + c * 512 + ((2 * k0) ^ ((c & 7) << 4)));
            }
#pragma unroll
            for (int j = 0; j < 4; ++j) {
#pragma unroll
                for (int kf = 0; kf < 4; ++kf)
                    acc[j] = mfma16(wf[j][kh * 4 + kf], hb[kf], acc[j]);
            }
#pragma unroll
            for (int j = 4; j < 6; ++j) {
#pragma unroll
                for (int kf = 0; kf < 4; ++kf) {
                    bf16x8 a = *(const bf16x8*)(wlds +
                        (((w * 2 + (j - 4)) * 8 + kh * 4 + kf) << 10) + l * 16);
                    acc[j] = mfma16(a, hb[kf], acc[j]);
                }
            }
        }

        // --- r,z statistics ---
#pragma unroll
        for (int g = 0; g < 2; ++g) {
            float s = 0.f, ss2 = 0.f;
#pragma unroll
            for (int jj = 0; jj < 2; ++jj) {
                int j = g * 2 + jj;
#pragma unroll
                for (int r = 0; r < 4; ++r) {
                    float p = acc[j][r] + (float)ihv[j][r];
                    s += p; ss2 += p * p;
                }
            }
            s += __shfl_xor(s, 16); ss2 += __shfl_xor(ss2, 16);
            s += __shfl_xor(s, 32); ss2 += __shfl_xor(ss2, 32);
            if (q == 0) *(float2*)(part + ((g * 8 + w) * 16 + c) * 2) = make_float2(s, ss2);
        }
        __syncthreads();
        if (w == 0 && l < 32) {
            int g = l >> 4;
            float S = 0.f, SQ = 0.f;
#pragma unroll
            for (int wv = 0; wv < 8; ++wv) {
                float2 pp = *(float2*)(part + ((g * 8 + wv) * 16 + c) * 2);
                S += pp.x; SQ += pp.y;
            }
            float m  = S * (1.f / 256.f);
            float v  = SQ * (1.f / 256.f) - m * m;
            float rs = __builtin_amdgcn_rsqf(v + 1e-5f);
            *(float2*)(mu + (g * 16 + c) * 2) = make_float2(m, rs);
        }
        __syncthreads();

        // --- finish r,z: y' = (pre-mu)*rstd*gamma' + beta'; act = rcp(1+exp2(y')) ---
        float rhat[2][4], zhat[2][4];
#pragma unroll
        for (int g = 0; g < 2; ++g) {
            float2 mr = *(float2*)(mu + (g * 16 + c) * 2);
#pragma unroll
            for (int jj = 0; jj < 2; ++jj) {
                int j = g * 2 + jj;
                int o0 = (w + 8 * j) * 16 + q * 4;
                f32x4 gam = *(f32x4*)(gb + o0);
                f32x4 bet = *(f32x4*)(gb + GG + o0);
#pragma unroll
                for (int r = 0; r < 4; ++r) {
                    float p  = acc[j][r] + (float)ihv[j][r];
                    float tt = mr.y * gam[r];
                    float y  = p * tt + (bet[r] - mr.x * tt);
                    float a  = __builtin_amdgcn_rcpf(1.f + __builtin_amdgcn_exp2f(y));
                    if (g == 0) rhat[jj][r] = a; else zhat[jj][r] = a;
                }
            }
        }

        // --- n preact + statistics (needs rhat; same lane holds the pair) ---
        float pn[2][4];
        {
            float s = 0.f, ss2 = 0.f;
#pragma unroll
            for (int jj = 0; jj < 2; ++jj) {
                int j = 4 + jj;
#pragma unroll
                for (int r = 0; r < 4; ++r) {
                    float p = (float)ihv[j][r] + rhat[jj][r] * acc[j][r];
                    pn[jj][r] = p; s += p; ss2 += p * p;
                }
            }
            s += __shfl_xor(s, 16); ss2 += __shfl_xor(ss2, 16);
            s += __shfl_xor(s, 32); ss2 += __shfl_xor(ss2, 32);
            if (q == 0) *(float2*)(part + ((16 + w) * 16 + c) * 2) = make_float2(s, ss2);
        }
        __syncthreads();
        if (w == 0 && l < 16) {
            float S = 0.f, SQ = 0.f;
#pragma unroll
            for (int wv = 0; wv < 8; ++wv) {
                float2 pp = *(float2*)(part + ((16 + wv) * 16 + c) * 2);
                S += pp.x; SQ += pp.y;
            }
            float m  = S * (1.f / 256.f);
            float v  = SQ * (1.f / 256.f) - m * m;
            float rs = __builtin_amdgcn_rsqf(v + 1e-5f);
            *(float2*)(mu + (32 + c) * 2) = make_float2(m, rs);
        }
        __syncthreads();

        // --- finish n, h update, writes ---
        {
            float2 mr = *(float2*)(mu + (32 + c) * 2);
            float* yt = yb + (size_t)t * HH;
#pragma unroll
            for (int jj = 0; jj < 2; ++jj) {
                int o0n = (w + 8 * (4 + jj)) * 16 + q * 4;
                int oh0 = o0n - 512;
                f32x4 gam = *(f32x4*)(gb + o0n);
                f32x4 bet = *(f32x4*)(gb + GG + o0n);
                char* haddr = hbuf + c * 512 + ((2 * oh0) ^ ((c & 7) << 4));
                bf16x4 hov = *(bf16x4*)haddr;
                f32x4 yv; bf16x4 hnv;
#pragma unroll
                for (int r = 0; r < 4; ++r) {
                    float p  = pn[jj][r];
                    float tt = mr.y * gam[r];
                    float y  = p * tt + (bet[r] - mr.x * tt);
                    float nh = 2.f * __builtin_amdgcn_rcpf(1.f + __builtin_amdgcn_exp2f(y)) - 1.f;
                    float z  = zhat[jj][r];
                    float hn = nh + z * ((float)hov[r] - nh);
                    yv[r] = hn; hnv[r] = (__bf16)hn;
                }
                *(bf16x4*)haddr = hnv;          // h for next step (bf16)
                *(f32x4*)(yt + oh0) = yv;       // output (fp32)
            }
        }
        __syncthreads();
    }
}

// ---------------------------------------------------------------------------
extern "C" void kernel_launch(void* const* d_in, const int* in_sizes, int n_in,
                              void* d_out, int out_size, void* d_ws, size_t ws_size,
                              hipStream_t stream)
{
    (void)in_sizes; (void)n_in; (void)out_size;
    const float* x    = (const float*)d_in[0];
    const float* hx   = (const float*)d_in[1];
    const float* W_ih = (const float*)d_in[2];
    const float* W_hh = (const float*)d_in[3];
    const float* gmm  = (const float*)d_in[4];
    const float* bta  = (const float*)d_in[5];
    float* Y = (float*)d_out;
    __bf16* ihws = (__bf16*)d_ws;

    // need S*B*768 bf16 = 201,326,592 bytes of workspace for the ih buffer
    if (ws_size < (size_t)SS * BB * GG * 2) return;  // fail fast (output stays poisoned)

    hipFuncSetAttribute((const void*)k_rec,
                        hipFuncAttributeMaxDynamicSharedMemorySize, 148864);

    for (int layer = 0; layer < 2; ++layer) {
        const float* X = (layer == 0) ? x : (const float*)Y;
        k_ih<<<dim3(3072), dim3(512), 0, stream>>>(
            X, W_ih + (size_t)layer * GG * HH, ihws);
        k_rec<<<dim3(8), dim3(512), 148864, stream>>>(
            ihws, W_hh + (size_t)layer * GG * HH,
            hx + (size_t)layer * BB * HH,
            gmm + (size_t)layer * GG, bta + (size_t)layer * GG, Y);
    }
}

// Round 2
// 5538.094 us; speedup vs baseline: 1.7183x; 1.7183x over previous
//
#include <hip/hip_runtime.h>
#include <cstdint>

#define BB 128
#define SS 1024
#define HH 256
#define GG 768
#define LOG2E 1.44269504088896340736f

typedef __attribute__((ext_vector_type(8))) __bf16 bf16x8;
typedef __attribute__((ext_vector_type(4))) __bf16 bf16x4;
typedef __attribute__((ext_vector_type(4))) float f32x4;

static __device__ __forceinline__ f32x4 mfma16(bf16x8 a, bf16x8 b, f32x4 c) {
    return __builtin_amdgcn_mfma_f32_16x16x32_bf16(a, b, c, 0, 0, 0);
}

static __device__ __forceinline__ bf16x8 load_w8(const float* __restrict__ p) {
    f32x4 a = *(const f32x4*)p;
    f32x4 b = *(const f32x4*)(p + 4);
    bf16x8 v;
    v[0] = (__bf16)a[0]; v[1] = (__bf16)a[1]; v[2] = (__bf16)a[2]; v[3] = (__bf16)a[3];
    v[4] = (__bf16)b[0]; v[5] = (__bf16)b[1]; v[6] = (__bf16)b[2]; v[7] = (__bf16)b[3];
    return v;
}

// LDS-only barrier: wait own LDS ops, barrier. Never drains vmcnt (global
// stores keep floating; global loads are waited at their register use).
#define LBAR() asm volatile("s_waitcnt lgkmcnt(0)\n\ts_barrier" ::: "memory")

// ih workspace layout (elements): ((t*16 + g16)*48 + tile)*128 + b8*16 + o
// tile = global out-tile 0..47 (gate r: 0-15, z: 16-31, n: 32-47)
static __device__ __forceinline__ size_t ih_off(int t, int g16, int T, int b8, int o) {
    return (((size_t)t * 16 + g16) * 48 + T) * 128 + b8 * 16 + o;
}

// ---------------------------------------------------------------------------
// K1: ih = X @ Wih^T, bf16, coalesced layout. grid (32 tblk, 8 grp), 512 thr.
// Wave w owns tiles w+8j: j=0..3 in VGPR, j=4,5 in LDS. X staged per-t in
// LDS (swizzled), double-buffered with register prefetch.
// ---------------------------------------------------------------------------
__global__ __launch_bounds__(512, 2) void k_ih(
    const float* __restrict__ X, const float* __restrict__ Wih,
    __bf16* __restrict__ ih)
{
    extern __shared__ __align__(16) char lds[];
    char* wlds = lds;               // 131072: 8 waves x 2 tiles x 8 frags x 1KB
    char* xst  = lds + 131072;      // 2 x 8192: X[16][256] bf16 swizzled

    const int tblk = blockIdx.x;    // 32 timesteps each
    const int grp  = blockIdx.y;    // 16 batches each
    const int tid = threadIdx.x;
    const int w = tid >> 6, l = tid & 63;
    const int c = l & 15, q = l >> 4;

    bf16x8 wf[4][8];
#pragma unroll
    for (int j = 0; j < 4; ++j) {
        const float* wp = Wih + (size_t)((w + 8 * j) * 16 + c) * HH + q * 8;
#pragma unroll
        for (int kf = 0; kf < 8; ++kf) wf[j][kf] = load_w8(wp + kf * 32);
    }
#pragma unroll
    for (int j = 4; j < 6; ++j) {
        const float* wp = Wih + (size_t)((w + 8 * j) * 16 + c) * HH + q * 8;
#pragma unroll
        for (int kf = 0; kf < 8; ++kf) {
            bf16x8 v = load_w8(wp + kf * 32);
            *(bf16x8*)(wlds + (((w * 2 + (j - 4)) * 8 + kf) << 10) + l * 16) = v;
        }
    }

    // stage t=0 into buf 0
    {
        int t0 = tblk * 32;
#pragma unroll
        for (int half = 0; half < 2; ++half) {
            int cc = half * 512 + tid;
            int b = cc >> 6, kc = (cc & 63) * 4;
            f32x4 v = *(const f32x4*)(X + ((size_t)(grp * 16 + b) * SS + t0) * HH + kc);
            bf16x4 o;
#pragma unroll
            for (int r = 0; r < 4; ++r) o[r] = (__bf16)v[r];
            *(bf16x4*)(xst + b * 512 + ((2 * kc) ^ ((b & 7) << 4))) = o;
        }
    }
    LBAR();

    const int sb = (tid >> 6) & 15;  // not used; silence nothing
    (void)sb;
#pragma unroll 1
    for (int tt = 0; tt < 32; ++tt) {
        const int t = tblk * 32 + tt;
        const int buf = tt & 1;
        // prefetch next timestep's X into regs
        f32x4 pf0, pf1;
        int bnx0 = 0, knx0 = 0, bnx1 = 0, knx1 = 0;
        if (tt + 1 < 32) {
            int tn = t + 1;
            int cc0 = tid;       bnx0 = cc0 >> 6; knx0 = (cc0 & 63) * 4;
            int cc1 = 512 + tid; bnx1 = cc1 >> 6; knx1 = (cc1 & 63) * 4;
            pf0 = *(const f32x4*)(X + ((size_t)(grp * 16 + bnx0) * SS + tn) * HH + knx0);
            pf1 = *(const f32x4*)(X + ((size_t)(grp * 16 + bnx1) * SS + tn) * HH + knx1);
        }

        f32x4 acc[6];
#pragma unroll
        for (int j = 0; j < 6; ++j) acc[j] = (f32x4){0.f, 0.f, 0.f, 0.f};
#pragma unroll
        for (int kh = 0; kh < 2; ++kh) {
            bf16x8 xb[4];
#pragma unroll
            for (int kf = 0; kf < 4; ++kf) {
                int k0 = kh * 128 + kf * 32 + q * 8;
                xb[kf] = *(const bf16x8*)(xst + buf * 8192 + c * 512 +
                                          ((2 * k0) ^ ((c & 7) << 4)));
            }
#pragma unroll
            for (int j = 0; j < 4; ++j)
#pragma unroll
                for (int kf = 0; kf < 4; ++kf)
                    acc[j] = mfma16(wf[j][kh * 4 + kf], xb[kf], acc[j]);
#pragma unroll
            for (int j = 4; j < 6; ++j)
#pragma unroll
                for (int kf = 0; kf < 4; ++kf) {
                    bf16x8 a = *(const bf16x8*)(wlds +
                        (((w * 2 + (j - 4)) * 8 + kh * 4 + kf) << 10) + l * 16);
                    acc[j] = mfma16(a, xb[kf], acc[j]);
                }
        }
        // store: D col=c=batch, rows q*4+r
        {
            int g16 = grp * 2 + (c >> 3), b8 = c & 7;
#pragma unroll
            for (int j = 0; j < 6; ++j) {
                bf16x4 o;
#pragma unroll
                for (int r = 0; r < 4; ++r) o[r] = (__bf16)acc[j][r];
                *(bf16x4*)(ih + ih_off(t, g16, w + 8 * j, b8, q * 4)) = o;
            }
        }
        // write prefetched stage into other buffer
        if (tt + 1 < 32) {
            bf16x4 o0, o1;
#pragma unroll
            for (int r = 0; r < 4; ++r) { o0[r] = (__bf16)pf0[r]; o1[r] = (__bf16)pf1[r]; }
            char* dst = xst + (buf ^ 1) * 8192;
            *(bf16x4*)(dst + bnx0 * 512 + ((2 * knx0) ^ ((bnx0 & 7) << 4))) = o0;
            *(bf16x4*)(dst + bnx1 * 512 + ((2 * knx1) ^ ((bnx1 & 7) << 4))) = o1;
        }
        LBAR();
    }
}

// ---------------------------------------------------------------------------
// K2: GRU scan. grid 16 (8 batches each), 512 thr / 8 waves. W_hh resident
// (4 tiles VGPR + 2 tiles LDS per wave). Post-MFMA fold via shfl_xor(8):
// lanes c<8 handle tiles {w, w+16, w+32}, lanes c>=8 tiles {w+8, w+24, w+40}
// for batch c&7 -> all 64 lanes useful in LN/act. 3 raw barriers/step.
// ---------------------------------------------------------------------------
__global__ __launch_bounds__(512, 2) void k_rec(
    const __bf16* __restrict__ ih, const float* __restrict__ Whh,
    const float* __restrict__ hx, const float* __restrict__ gamma,
    const float* __restrict__ beta, float* __restrict__ Y)
{
    extern __shared__ __align__(16) char lds[];
    char*  wlds = lds;                       // 131072
    char*  hbuf = lds + 131072;              // 4096: h[8][256] bf16 swizzled
    float* part = (float*)(lds + 135168);    // 3 gates x 8 b x 20 floats = 1920B
    float* gb   = (float*)(lds + 137088);    // 6144: prescaled gamma|beta
    // total 143232

    const int grp = blockIdx.x;              // 0..15, batches grp*8..+8
    const int tid = threadIdx.x;
    const int w = tid >> 6, l = tid & 63;
    const int c = l & 15, q = l >> 4;
    const int b8 = c & 7, chi = c >> 3;

    for (int idx = tid; idx < GG; idx += 512) {
        float sc = (idx >= 512) ? (-2.0f * LOG2E) : (-LOG2E);
        gb[idx]      = gamma[idx] * sc;
        gb[GG + idx] = beta[idx]  * sc;
    }
    for (int idx = tid; idx < 8 * HH; idx += 512) {
        int b = idx >> 8, k = idx & 255;
        *(__bf16*)(hbuf + b * 512 + ((2 * k) ^ ((b & 7) << 4))) =
            (__bf16)hx[(size_t)(grp * 8 + b) * HH + k];
    }
    bf16x8 wf[4][8];
#pragma unroll
    for (int j = 0; j < 4; ++j) {
        const float* wp = Whh + (size_t)((w + 8 * j) * 16 + c) * HH + q * 8;
#pragma unroll
        for (int kf = 0; kf < 8; ++kf) wf[j][kf] = load_w8(wp + kf * 32);
    }
#pragma unroll
    for (int j = 4; j < 6; ++j) {
        const float* wp = Whh + (size_t)((w + 8 * j) * 16 + c) * HH + q * 8;
#pragma unroll
        for (int kf = 0; kf < 8; ++kf) {
            bf16x8 v = load_w8(wp + kf * 32);
            *(bf16x8*)(wlds + (((w * 2 + (j - 4)) * 8 + kf) << 10) + l * 16) = v;
        }
    }
    __syncthreads();   // preamble: full drain once is fine

    // per-lane LN/act tile set: T_j2 = w + 8*chi + 16*j2  (j2: 0=r, 1=z, 2=n)
    const int o0base = (w + 8 * chi) * 16 + q * 4;   // + j2*256 for gate
    const int ho = w * 16 + chi * 128 + q * 4;       // h index of n tile
    float* yb = Y + (size_t)(grp * 8 + b8) * SS * HH;

    bf16x4 ihc[3], ihn[3];
    {
        size_t base = ih_off(0, grp, 0, b8, q * 4);
#pragma unroll
        for (int j2 = 0; j2 < 3; ++j2)
            ihc[j2] = *(const bf16x4*)(ih + base + (size_t)(w + 8 * chi + 16 * j2) * 128);
    }

#pragma unroll 1
    for (int t = 0; t < SS; ++t) {
        // prefetch next step's ih (hidden under the whole step)
        {
            int tn = (t + 1 < SS) ? t + 1 : t;
            size_t base = ih_off(tn, grp, 0, b8, q * 4);
#pragma unroll
            for (int j2 = 0; j2 < 3; ++j2)
                ihn[j2] = *(const bf16x4*)(ih + base + (size_t)(w + 8 * chi + 16 * j2) * 128);
        }

        f32x4 acc[6];
#pragma unroll
        for (int j = 0; j < 6; ++j) acc[j] = (f32x4){0.f, 0.f, 0.f, 0.f};
#pragma unroll
        for (int kh = 0; kh < 2; ++kh) {
            bf16x8 hb[4];
#pragma unroll
            for (int kf = 0; kf < 4; ++kf) {
                int k0 = kh * 128 + kf * 32 + q * 8;
                hb[kf] = *(const bf16x8*)(hbuf + b8 * 512 + ((2 * k0) ^ (b8 << 4)));
            }
#pragma unroll
            for (int j = 0; j < 4; ++j)
#pragma unroll
                for (int kf = 0; kf < 4; ++kf)
                    acc[j] = mfma16(wf[j][kh * 4 + kf], hb[kf], acc[j]);
#pragma unroll
            for (int j = 4; j < 6; ++j)
#pragma unroll
                for (int kf = 0; kf < 4; ++kf) {
                    bf16x8 a = *(const bf16x8*)(wlds +
                        (((w * 2 + (j - 4)) * 8 + kh * 4 + kf) << 10) + l * 16);
                    acc[j] = mfma16(a, hb[kf], acc[j]);
                }
        }

        // fold: odd tiles -> high c-half; pa[j2] = recurrent preact for this lane
        f32x4 pa[3];
#pragma unroll
        for (int j2 = 0; j2 < 3; ++j2) {
            f32x4 hi = acc[2 * j2 + 1];
            f32x4 sw;
#pragma unroll
            for (int r = 0; r < 4; ++r) sw[r] = __shfl_xor(hi[r], 8);
            pa[j2] = chi ? sw : acc[2 * j2];
        }

        // r,z stats
        float s0 = 0.f, t0 = 0.f, s1 = 0.f, t1 = 0.f;
#pragma unroll
        for (int r = 0; r < 4; ++r) {
            float p0 = pa[0][r] + (float)ihc[0][r]; pa[0][r] = p0; s0 += p0; t0 += p0 * p0;
            float p1 = pa[1][r] + (float)ihc[1][r]; pa[1][r] = p1; s1 += p1; t1 += p1 * p1;
        }
        s0 += __shfl_xor(s0, 16); t0 += __shfl_xor(t0, 16);
        s0 += __shfl_xor(s0, 32); t0 += __shfl_xor(t0, 32);
        s0 += __shfl_xor(s0, 8);  t0 += __shfl_xor(t0, 8);
        s1 += __shfl_xor(s1, 16); t1 += __shfl_xor(t1, 16);
        s1 += __shfl_xor(s1, 32); t1 += __shfl_xor(t1, 32);
        s1 += __shfl_xor(s1, 8);  t1 += __shfl_xor(t1, 8);
        if (l < 8) {
            *(float2*)(part + (0 * 8 + l) * 20 + w * 2) = make_float2(s0, t0);
            *(float2*)(part + (1 * 8 + l) * 20 + w * 2) = make_float2(s1, t1);
        }
        LBAR();  // BAR1

        // mu/rstd for r,z (all waves, vectorized, padded stride 80B)
        float2 mrz[2];
#pragma unroll
        for (int g = 0; g < 2; ++g) {
            const f32x4* pp = (const f32x4*)(part + (g * 8 + b8) * 20);
            f32x4 a = pp[0] + pp[1] + pp[2] + pp[3];
            float S = a[0] + a[2], Q2 = a[1] + a[3];
            float m = S * (1.f / 256.f);
            float v = Q2 * (1.f / 256.f) - m * m;
            mrz[g] = make_float2(m, __builtin_amdgcn_rsqf(v + 1e-5f));
        }

        // finish r,z
        float rz[2][4];
#pragma unroll
        for (int g = 0; g < 2; ++g) {
            int o0 = o0base + g * 256;
            f32x4 gam = *(f32x4*)(gb + o0);
            f32x4 bet = *(f32x4*)(gb + GG + o0);
#pragma unroll
            for (int r = 0; r < 4; ++r) {
                float sf = mrz[g].y * gam[r];
                float y  = pa[g][r] * sf + (bet[r] - mrz[g].x * sf);
                rz[g][r] = __builtin_amdgcn_rcpf(1.f + __builtin_amdgcn_exp2f(y));
            }
        }

        // n preact + stats
        float pn[4]; float sn = 0.f, tn2 = 0.f;
#pragma unroll
        for (int r = 0; r < 4; ++r) {
            float p = (float)ihc[2][r] + rz[0][r] * pa[2][r];
            pn[r] = p; sn += p; tn2 += p * p;
        }
        sn += __shfl_xor(sn, 16); tn2 += __shfl_xor(tn2, 16);
        sn += __shfl_xor(sn, 32); tn2 += __shfl_xor(tn2, 32);
        sn += __shfl_xor(sn, 8);  tn2 += __shfl_xor(tn2, 8);
        if (l < 8)
            *(float2*)(part + (2 * 8 + l) * 20 + w * 2) = make_float2(sn, tn2);
        LBAR();  // BAR2

        {
            const f32x4* pp = (const f32x4*)(part + (2 * 8 + b8) * 20);
            f32x4 a = pp[0] + pp[1] + pp[2] + pp[3];
            float S = a[0] + a[2], Q2 = a[1] + a[3];
            float m = S * (1.f / 256.f);
            float v = Q2 * (1.f / 256.f) - m * m;
            float rs = __builtin_amdgcn_rsqf(v + 1e-5f);

            int o0 = o0base + 512;
            f32x4 gam = *(f32x4*)(gb + o0);
            f32x4 bet = *(f32x4*)(gb + GG + o0);
            char* haddr = hbuf + b8 * 512 + ((2 * ho) ^ (b8 << 4));
            bf16x4 hov = *(bf16x4*)haddr;
            f32x4 yv; bf16x4 hnv;
#pragma unroll
            for (int r = 0; r < 4; ++r) {
                float sf = rs * gam[r];
                float y  = pn[r] * sf + (bet[r] - m * sf);
                float nh = 2.f * __builtin_amdgcn_rcpf(1.f + __builtin_amdgcn_exp2f(y)) - 1.f;
                float hn = nh + rz[1][r] * ((float)hov[r] - nh);
                yv[r] = hn; hnv[r] = (__bf16)hn;
            }
            *(bf16x4*)haddr = hnv;
            *(f32x4*)(yb + (size_t)t * HH + ho) = yv;   // store floats, never drained
        }
#pragma unroll
        for (int j2 = 0; j2 < 3; ++j2) ihc[j2] = ihn[j2];
        LBAR();  // BAR3
    }
}

// ---------------------------------------------------------------------------
extern "C" void kernel_launch(void* const* d_in, const int* in_sizes, int n_in,
                              void* d_out, int out_size, void* d_ws, size_t ws_size,
                              hipStream_t stream)
{
    (void)in_sizes; (void)n_in; (void)out_size;
    const float* x    = (const float*)d_in[0];
    const float* hx   = (const float*)d_in[1];
    const float* W_ih = (const float*)d_in[2];
    const float* W_hh = (const float*)d_in[3];
    const float* gmm  = (const float*)d_in[4];
    const float* bta  = (const float*)d_in[5];
    float* Y = (float*)d_out;
    __bf16* ihws = (__bf16*)d_ws;

    if (ws_size < (size_t)SS * BB * GG * 2) return;  // need 192 MiB scratch

    hipFuncSetAttribute((const void*)k_ih,
                        hipFuncAttributeMaxDynamicSharedMemorySize, 147456);
    hipFuncSetAttribute((const void*)k_rec,
                        hipFuncAttributeMaxDynamicSharedMemorySize, 143232);

    for (int layer = 0; layer < 2; ++layer) {
        const float* X = (layer == 0) ? x : (const float*)Y;
        k_ih<<<dim3(32, 8), dim3(512), 147456, stream>>>(
            X, W_ih + (size_t)layer * GG * HH, ihws);
        k_rec<<<dim3(16), dim3(512), 143232, stream>>>(
            ihws, W_hh + (size_t)layer * GG * HH,
            hx + (size_t)layer * BB * HH,
            gmm + (size_t)layer * GG, bta + (size_t)layer * GG, Y);
    }
}

// Round 3
// 3967.573 us; speedup vs baseline: 2.3985x; 1.3958x over previous
//
#include <hip/hip_runtime.h>
#include <cstdint>

#define BB 128
#define SS 1024
#define HH 256
#define GG 768
#define DD 64                      // ring depth (power of 2)
#define LOG2E 1.44269504088896340736f

typedef __attribute__((ext_vector_type(8))) __bf16 bf16x8;
typedef __attribute__((ext_vector_type(4))) __bf16 bf16x4;
typedef __attribute__((ext_vector_type(4))) float f32x4;

static __device__ __forceinline__ f32x4 mfma16(bf16x8 a, bf16x8 b, f32x4 c) {
    return __builtin_amdgcn_mfma_f32_16x16x32_bf16(a, b, c, 0, 0, 0);
}

static __device__ __forceinline__ bf16x8 load_w8(const float* __restrict__ p) {
    f32x4 a = *(const f32x4*)p;
    f32x4 b = *(const f32x4*)(p + 4);
    bf16x8 v;
    v[0] = (__bf16)a[0]; v[1] = (__bf16)a[1]; v[2] = (__bf16)a[2]; v[3] = (__bf16)a[3];
    v[4] = (__bf16)b[0]; v[5] = (__bf16)b[1]; v[6] = (__bf16)b[2]; v[7] = (__bf16)b[3];
    return v;
}

// LDS-only barrier (global stores keep floating) / full-drain barrier
#define LBAR() asm volatile("s_waitcnt lgkmcnt(0)\n\ts_barrier" ::: "memory")
#define VBAR() asm volatile("s_waitcnt vmcnt(0) lgkmcnt(0)\n\ts_barrier" ::: "memory")

// ring element offset: slot-major, tile T=0..47, 8 batches x 16 outs
static __device__ __forceinline__ size_t ring_off(int t, int g, int T, int b8, int o) {
    return (((size_t)(t & (DD - 1)) * 16 + g) * 48 + T) * 128 + b8 * 16 + o;
}

// spin until *p >= need (relaxed polls, one acquire fence on success)
static __device__ __forceinline__ int wait_ge(int* p, int need) {
    int v = __hip_atomic_load(p, __ATOMIC_RELAXED, __HIP_MEMORY_SCOPE_AGENT);
    while (v < need) {
        __builtin_amdgcn_s_sleep(8);
        v = __hip_atomic_load(p, __ATOMIC_RELAXED, __HIP_MEMORY_SCOPE_AGENT);
    }
    __builtin_amdgcn_fence(__ATOMIC_ACQUIRE, "agent");
    return v;
}

static __device__ __forceinline__ void publish(int* p, int v) {
    __hip_atomic_store(p, v, __ATOMIC_RELEASE, __HIP_MEMORY_SCOPE_AGENT);
}

// load the 48 W-tiles for this WG: wave w holds tiles w+8j, j=0..3 in VGPR,
// j=4,5 staged to LDS (16B/lane frags)
static __device__ __forceinline__ void load_wfrags(
    const float* __restrict__ W, char* wlds, bf16x8 (&wf)[4][8],
    int w, int l, int c, int q)
{
#pragma unroll
    for (int j = 0; j < 4; ++j) {
        const float* wp = W + (size_t)((w + 8 * j) * 16 + c) * HH + q * 8;
#pragma unroll
        for (int kf = 0; kf < 8; ++kf) wf[j][kf] = load_w8(wp + kf * 32);
    }
#pragma unroll
    for (int j = 4; j < 6; ++j) {
        const float* wp = W + (size_t)((w + 8 * j) * 16 + c) * HH + q * 8;
#pragma unroll
        for (int kf = 0; kf < 8; ++kf) {
            bf16x8 v = load_w8(wp + kf * 32);
            *(bf16x8*)(wlds + (((w * 2 + (j - 4)) * 8 + kf) << 10) + l * 16) = v;
        }
    }
}

// 768x8(x16-padded) GEMM: 48 MFMAs/wave over K=256 from a swizzled LDS
// B-buffer (8 rows x 256 bf16, row stride 512B, byte ^= (row&7)<<4)
static __device__ __forceinline__ void gemm6(
    f32x4 (&acc)[6], const char* bsrc, const char* wlds,
    const bf16x8 (&wf)[4][8], int w, int l, int q, int b8)
{
#pragma unroll
    for (int kh = 0; kh < 2; ++kh) {
        bf16x8 hb[4];
#pragma unroll
        for (int kf = 0; kf < 4; ++kf) {
            int k0 = kh * 128 + kf * 32 + q * 8;
            hb[kf] = *(const bf16x8*)(bsrc + b8 * 512 + ((2 * k0) ^ (b8 << 4)));
        }
#pragma unroll
        for (int j = 0; j < 4; ++j)
#pragma unroll
            for (int kf = 0; kf < 4; ++kf)
                acc[j] = mfma16(wf[j][kh * 4 + kf], hb[kf], acc[j]);
#pragma unroll
        for (int j = 4; j < 6; ++j)
#pragma unroll
            for (int kf = 0; kf < 4; ++kf) {
                bf16x8 a = *(const bf16x8*)(wlds +
                    (((w * 2 + (j - 4)) * 8 + kh * 4 + kf) << 10) + l * 16);
                acc[j] = mfma16(a, hb[kf], acc[j]);
            }
    }
}

// ---------------------------------------------------------------------------
// Fused 4-stage pipeline. 64 WGs x 512 thr: role = bid>>4, g = bid&15.
//   role 0: L0ih (x -> ring0)        role 1: L0rec (ring0 -> Y=h0, prog_y)
//   role 2: L1ih (Y=h0 -> ring1)     role 3: L1rec (ring1 -> Y=h1)
// Rings + flags live in d_ws. Flags: (kind*16+g)*32 ints, kind 0=ih0,
// 1=rec0(Y), 2=ih1, 3=rec1. Progress = #steps completed.
// ---------------------------------------------------------------------------
__global__ __launch_bounds__(512, 2) void k_fused(
    const float* __restrict__ x, const float* __restrict__ hx,
    const float* __restrict__ W_ih, const float* __restrict__ W_hh,
    const float* __restrict__ gamma, const float* __restrict__ beta,
    float* __restrict__ Y, char* __restrict__ ws)
{
    extern __shared__ __align__(16) char lds[];
    const int bid = blockIdx.x;
    const int role = bid >> 4;
    const int g = bid & 15;
    const int layer = role >> 1;

    __bf16* ring0 = (__bf16*)ws;
    __bf16* ring1 = (__bf16*)(ws + (64u << 20));
    int* flagbase = (int*)(ws + (128u << 20));
#define FLAG(kind, gg) (flagbase + ((kind) * 16 + (gg)) * 32)

    const int tid = threadIdx.x;
    const int w = tid >> 6, l = tid & 63;
    const int c = l & 15, q = l >> 4;
    const int b8 = c & 7, chi = c >> 3;

    char* wlds = lds;                        // 131072 B: W tiles j=4,5

    if (!(role & 1)) {
        // ================= ih stage =================
        char* xst = lds + 131072;            // 2 x 4096: input[8][256] bf16 swz
        const float* in = layer ? (const float*)Y : x;
        const float* W = W_ih + (size_t)layer * GG * HH;
        __bf16* ring = layer ? ring1 : ring0;
        int* p_self = FLAG(layer ? 2 : 0, g);
        int* p_dep  = layer ? FLAG(1, g) : nullptr;
        int* p_bp   = FLAG(layer ? 3 : 1, g);

        bf16x8 wf[4][8];
        load_wfrags(W, wlds, wf, w, l, c, q);
        __syncthreads();

        const int stb = tid >> 6;            // staging: batch 0..7
        const int stk = (tid & 63) * 4;      // k offset 0..252
        int kd = 0, kc = 0;

#pragma unroll 1
        for (int t = 0; t < SS; ++t) {
            if (t >= DD && kc < t - DD + 1) kc = wait_ge(p_bp, t - DD + 1);
            if (p_dep && kd < t + 1) kd = wait_ge(p_dep, t + 1);
            {
                f32x4 v = *(const f32x4*)(in + ((size_t)(g * 8 + stb) * SS + t) * HH + stk);
                bf16x4 o;
#pragma unroll
                for (int r = 0; r < 4; ++r) o[r] = (__bf16)v[r];
                *(bf16x4*)(xst + (t & 1) * 4096 + stb * 512 +
                           ((2 * stk) ^ ((stb & 7) << 4))) = o;
            }
            LBAR();
            f32x4 acc[6];
#pragma unroll
            for (int j = 0; j < 6; ++j) acc[j] = (f32x4){0.f, 0.f, 0.f, 0.f};
            gemm6(acc, xst + (t & 1) * 4096, wlds, wf, w, l, q, b8);
            if (c < 8) {
                size_t base = ring_off(t, g, 0, b8, q * 4);
#pragma unroll
                for (int j = 0; j < 6; ++j) {
                    bf16x4 o;
#pragma unroll
                    for (int r = 0; r < 4; ++r) o[r] = (__bf16)acc[j][r];
                    *(bf16x4*)(ring + base + (size_t)(w + 8 * j) * 128) = o;
                }
            }
            VBAR();
            if (tid == 0) publish(p_self, t + 1);
        }
    } else {
        // ================= rec stage =================
        char*  hbuf = lds + 131072;          // 4096: h[8][256] bf16 swz
        float* part = (float*)(lds + 135168);// 3 gates x 8 b x 20 floats
        float* gb   = (float*)(lds + 137088);// 6144: prescaled gamma|beta

        const __bf16* ring = layer ? ring1 : ring0;
        const float* Whh = W_hh + (size_t)layer * GG * HH;
        const float* gmm = gamma + (size_t)layer * GG;
        const float* bta = beta + (size_t)layer * GG;
        const float* hx0 = hx + (size_t)layer * BB * HH;
        int* p_src  = FLAG(layer ? 2 : 0, g);
        int* p_self = FLAG(layer ? 3 : 1, g);
        const int pubmask = layer ? 3 : 1;   // publish every 2 (L0) / 4 (L1)

        for (int idx = tid; idx < GG; idx += 512) {
            float sc = (idx >= 512) ? (-2.0f * LOG2E) : (-LOG2E);
            gb[idx]      = gmm[idx] * sc;
            gb[GG + idx] = bta[idx] * sc;
        }
        for (int idx = tid; idx < 8 * HH; idx += 512) {
            int b = idx >> 8, k = idx & 255;
            *(__bf16*)(hbuf + b * 512 + ((2 * k) ^ ((b & 7) << 4))) =
                (__bf16)hx0[(size_t)(g * 8 + b) * HH + k];
        }
        bf16x8 wf[4][8];
        load_wfrags(Whh, wlds, wf, w, l, c, q);
        __syncthreads();

        const int o0base = (w + 8 * chi) * 16 + q * 4;
        const int ho = w * 16 + chi * 128 + q * 4;
        float* yb = Y + (size_t)(g * 8 + b8) * SS * HH;

        int kp = wait_ge(p_src, 1);
        bf16x4 ihc[3], ihn[3];
        {
            size_t base = ring_off(0, g, 0, b8, q * 4);
#pragma unroll
            for (int j2 = 0; j2 < 3; ++j2)
                ihc[j2] = *(const bf16x4*)(ring + base + (size_t)(w + 8 * chi + 16 * j2) * 128);
        }

#pragma unroll 1
        for (int t = 0; t < SS; ++t) {
            int need = (t + 2 < SS) ? t + 2 : SS;
            if (kp < need) kp = wait_ge(p_src, need);
            {
                int tn = (t + 1 < SS) ? t + 1 : t;
                size_t base = ring_off(tn, g, 0, b8, q * 4);
#pragma unroll
                for (int j2 = 0; j2 < 3; ++j2)
                    ihn[j2] = *(const bf16x4*)(ring + base + (size_t)(w + 8 * chi + 16 * j2) * 128);
            }

            f32x4 acc[6];
#pragma unroll
            for (int j = 0; j < 6; ++j) acc[j] = (f32x4){0.f, 0.f, 0.f, 0.f};
            gemm6(acc, hbuf, wlds, wf, w, l, q, b8);

            // lane's tiles: w+8chi+16j2; B-cols c and c^8 duplicate, so the
            // odd-tile values for chi=1 lanes are already in acc[2j2+1].
            f32x4 pa[3];
#pragma unroll
            for (int j2 = 0; j2 < 3; ++j2)
                pa[j2] = chi ? acc[2 * j2 + 1] : acc[2 * j2];

            // r,z stats
            float s0 = 0.f, t0 = 0.f, s1 = 0.f, t1 = 0.f;
#pragma unroll
            for (int r = 0; r < 4; ++r) {
                float p0 = pa[0][r] + (float)ihc[0][r]; pa[0][r] = p0; s0 += p0; t0 += p0 * p0;
                float p1 = pa[1][r] + (float)ihc[1][r]; pa[1][r] = p1; s1 += p1; t1 += p1 * p1;
            }
            s0 += __shfl_xor(s0, 16); t0 += __shfl_xor(t0, 16);
            s0 += __shfl_xor(s0, 32); t0 += __shfl_xor(t0, 32);
            s0 += __shfl_xor(s0, 8);  t0 += __shfl_xor(t0, 8);
            s1 += __shfl_xor(s1, 16); t1 += __shfl_xor(t1, 16);
            s1 += __shfl_xor(s1, 32); t1 += __shfl_xor(t1, 32);
            s1 += __shfl_xor(s1, 8);  t1 += __shfl_xor(t1, 8);
            if (l < 8) {
                *(float2*)(part + (0 * 8 + l) * 20 + w * 2) = make_float2(s0, t0);
                *(float2*)(part + (1 * 8 + l) * 20 + w * 2) = make_float2(s1, t1);
            }
            LBAR();  // BAR1

            float2 mrz[2];
#pragma unroll
            for (int gg = 0; gg < 2; ++gg) {
                const f32x4* pp = (const f32x4*)(part + (gg * 8 + b8) * 20);
                f32x4 a = pp[0] + pp[1] + pp[2] + pp[3];
                float S = a[0] + a[2], Q2 = a[1] + a[3];
                float m = S * (1.f / 256.f);
                float v = Q2 * (1.f / 256.f) - m * m;
                mrz[gg] = make_float2(m, __builtin_amdgcn_rsqf(v + 1e-5f));
            }

            float rz[2][4];
#pragma unroll
            for (int gg = 0; gg < 2; ++gg) {
                int o0 = o0base + gg * 256;
                f32x4 gam = *(f32x4*)(gb + o0);
                f32x4 bet = *(f32x4*)(gb + GG + o0);
#pragma unroll
                for (int r = 0; r < 4; ++r) {
                    float sf = mrz[gg].y * gam[r];
                    float y  = pa[gg][r] * sf + (bet[r] - mrz[gg].x * sf);
                    rz[gg][r] = __builtin_amdgcn_rcpf(1.f + __builtin_amdgcn_exp2f(y));
                }
            }

            float pn[4]; float sn = 0.f, tn2 = 0.f;
#pragma unroll
            for (int r = 0; r < 4; ++r) {
                float p = (float)ihc[2][r] + rz[0][r] * pa[2][r];
                pn[r] = p; sn += p; tn2 += p * p;
            }
            sn += __shfl_xor(sn, 16); tn2 += __shfl_xor(tn2, 16);
            sn += __shfl_xor(sn, 32); tn2 += __shfl_xor(tn2, 32);
            sn += __shfl_xor(sn, 8);  tn2 += __shfl_xor(tn2, 8);
            if (l < 8)
                *(float2*)(part + (2 * 8 + l) * 20 + w * 2) = make_float2(sn, tn2);
            LBAR();  // BAR2

            {
                const f32x4* pp = (const f32x4*)(part + (2 * 8 + b8) * 20);
                f32x4 a = pp[0] + pp[1] + pp[2] + pp[3];
                float S = a[0] + a[2], Q2 = a[1] + a[3];
                float m = S * (1.f / 256.f);
                float v = Q2 * (1.f / 256.f) - m * m;
                float rs = __builtin_amdgcn_rsqf(v + 1e-5f);

                int o0 = o0base + 512;
                f32x4 gam = *(f32x4*)(gb + o0);
                f32x4 bet = *(f32x4*)(gb + GG + o0);
                char* haddr = hbuf + b8 * 512 + ((2 * ho) ^ (b8 << 4));
                bf16x4 hov = *(bf16x4*)haddr;
                f32x4 yv; bf16x4 hnv;
#pragma unroll
                for (int r = 0; r < 4; ++r) {
                    float sf = rs * gam[r];
                    float y  = pn[r] * sf + (bet[r] - m * sf);
                    float nh = 2.f * __builtin_amdgcn_rcpf(1.f + __builtin_amdgcn_exp2f(y)) - 1.f;
                    float hn = nh + rz[1][r] * ((float)hov[r] - nh);
                    yv[r] = hn; hnv[r] = (__bf16)hn;
                }
                *(bf16x4*)haddr = hnv;
                *(f32x4*)(yb + (size_t)t * HH + ho) = yv;
            }
#pragma unroll
            for (int j2 = 0; j2 < 3; ++j2) ihc[j2] = ihn[j2];

            if ((t & pubmask) == pubmask) {
                VBAR();  // drain Y stores, then publish progress
                if (tid == 0) publish(p_self, t + 1);
            } else {
                LBAR();  // BAR3
            }
        }
    }
#undef FLAG
}

// ---------------------------------------------------------------------------
extern "C" void kernel_launch(void* const* d_in, const int* in_sizes, int n_in,
                              void* d_out, int out_size, void* d_ws, size_t ws_size,
                              hipStream_t stream)
{
    (void)in_sizes; (void)n_in; (void)out_size;
    const float* x    = (const float*)d_in[0];
    const float* hx   = (const float*)d_in[1];
    const float* W_ih = (const float*)d_in[2];
    const float* W_hh = (const float*)d_in[3];
    const float* gmm  = (const float*)d_in[4];
    const float* bta  = (const float*)d_in[5];
    float* Y = (float*)d_out;
    char* ws = (char*)d_ws;

    // ws usage: ring0 [0,12.6MB) ring1 [64MiB,+12.6MB) flags [128MiB,+8KB)
    if (ws_size < (size_t)SS * BB * GG * 2) return;

    hipFuncSetAttribute((const void*)k_fused,
                        hipFuncAttributeMaxDynamicSharedMemorySize, 143232);

    // zero the progress flags (re-zeroed on every replay)
    hipMemsetAsync(ws + (128u << 20), 0, 64 * 32 * 4, stream);

    k_fused<<<dim3(64), dim3(512), 143232, stream>>>(
        x, hx, W_ih, W_hh, gmm, bta, Y, ws);
}